// Round 6
// baseline (395.631 us; speedup 1.0000x reference)
//
#include <hip/hip_runtime.h>
#include <hip/hip_bf16.h>

#define LL 80
#define NPIX 784
#define PBATCH 15680

#define DI __device__ __forceinline__

typedef short s8v __attribute__((ext_vector_type(8)));     // 8 bf16 = 16B
typedef short short4v __attribute__((ext_vector_type(4))); // 4 bf16 = 8B
typedef float f32x4 __attribute__((ext_vector_type(4)));   // MFMA acc

DI float b2f(__hip_bfloat16 x) { return __bfloat162float(x); }
DI float s2f(short h) { return __uint_as_float(((unsigned int)(unsigned short)h) << 16); }

// f32 -> bf16 bits, round-nearest-even
DI short f2b(float x) {
    unsigned int b = __float_as_uint(x);
    b += 0x7fffu + ((b >> 16) & 1u);
    return (short)(b >> 16);
}

// F=1: buffer holds f32; F=0: buffer holds bf16
template <int F> DI float LD(const void* p, int i) {
    if (F) return ((const float*)p)[i];
    return b2f(((const __hip_bfloat16*)p)[i]);
}
DI float LDf(int f, const void* p, int i) { return f ? ((const float*)p)[i] : b2f(((const __hip_bfloat16*)p)[i]); }

DI float fast_tanh(float x) {
    float e = __expf(2.0f * x);
    return 1.0f - 2.0f / (e + 1.0f);
}
DI float fast_sigmoid(float x) { return 1.0f / (1.0f + __expf(-x)); }

// ---------------- dtype probe (proven R3-R6) ----------------
__global__ __launch_bounds__(256) void detect_dtype(const void* probe, int n, int* flag) {
    __shared__ int bad;
    if (threadIdx.x == 0) bad = 0;
    __syncthreads();
    int c = 0;
    for (int i = threadIdx.x; i < n; i += 256) {
        float v = b2f(((const __hip_bfloat16*)probe)[i]);
        if (!(fabsf(v) < 1000.0f)) c++;
    }
    if (c) atomicAdd(&bad, c);
    __syncthreads();
    if (threadIdx.x == 0) *flag = (bad > 8) ? 1 : 0;   // 1 => inputs are f32
}

// ---------------- prep sub-parts ----------------
DI void cvt_part(int f, const void* src, short* __restrict__ dst, int blk, int n) {
    int i0 = (blk * 256 + threadIdx.x) * 4;
    if (i0 >= n) return;
    if (f) {
        float4 v = *(const float4*)((const float*)src + i0);
        short4v o = { f2b(v.x), f2b(v.y), f2b(v.z), f2b(v.w) };
        *(short4v*)(dst + i0) = o;
    } else {
        *(short4v*)(dst + i0) = *(const short4v*)((const short*)src + i0);
    }
}

// cvt with K-pad: src rows are 300 wide, dst rows 320 wide (zeros for k>=300)
DI void cvt_pad(int f, const void* src, short* __restrict__ dst, int blk, int n) {
    int i0 = (blk * 256 + threadIdx.x) * 4;
    if (i0 >= n) return;
    int row = i0 / 320;
    int k = i0 - row * 320;
    short4v o = {0, 0, 0, 0};
    if (k < 300) {
        if (f) {
            float4 v = *(const float4*)((const float*)src + row * 300 + k);
            o.x = f2b(v.x); o.y = f2b(v.y); o.z = f2b(v.z); o.w = f2b(v.w);
        } else {
            o = *(const short4v*)((const short*)src + row * 300 + k);
        }
    }
    *(short4v*)(dst + i0) = o;
}

// wcat[4096][1024]: rows 0-1023 w3 folded, 1024-2047 w4 folded, 2048-3071 w5 folded, 3072-4095 u3
// (proven R2 layout — R4's K-concat/interleave variant was latency-bound; keep this.)
DI void wcat_part(int f, const void* w3, const void* w4, const void* w5, const void* u3,
                  short* __restrict__ wcat, int blk) {
    int i0 = (blk * 256 + threadIdx.x) * 4;
    int nr = i0 >> 10, k = i0 & 1023;
    int j = nr >> 10, r = nr & 1023;
    const void* W = (j == 0) ? w3 : (j == 1) ? w4 : (j == 2) ? w5 : u3;
    float4 v;
    if (j < 3) {
        if (f) {
            float4 x = *(const float4*)((const float*)W + r * 2048 + k);
            float4 y = *(const float4*)((const float*)W + r * 2048 + 1024 + k);
            v.x = x.x + y.x; v.y = x.y + y.y; v.z = x.z + y.z; v.w = x.w + y.w;
        } else {
            const short* Ws = (const short*)W;
            short4v x = *(const short4v*)(Ws + r * 2048 + k);
            short4v y = *(const short4v*)(Ws + r * 2048 + 1024 + k);
            v.x = s2f(x.x) + s2f(y.x); v.y = s2f(x.y) + s2f(y.y);
            v.z = s2f(x.z) + s2f(y.z); v.w = s2f(x.w) + s2f(y.w);
        }
    } else {
        if (f) v = *(const float4*)((const float*)W + r * 1024 + k);
        else {
            short4v x = *(const short4v*)((const short*)W + r * 1024 + k);
            v.x = s2f(x.x); v.y = s2f(x.y); v.z = s2f(x.z); v.w = s2f(x.w);
        }
    }
    short4v o = { f2b(v.x), f2b(v.y), f2b(v.z), f2b(v.w) };
    *(short4v*)(wcat + i0) = o;
}

// u = fca_w @ fc3_w, split 16-way over j into partials.
template <int F>
DI void prep_upart(const void* fc3_w, const void* fca_w,
                   float* __restrict__ u_part, int blk) {
    int kseg = blk >> 4, jseg = blk & 15;
    int k = kseg * 256 + threadIdx.x;
    int j0 = jseg * 64;
    float acc = 0.f;
    for (int j = j0; j < j0 + 64; j++)
        acc += LD<F>(fca_w, j) * LD<F>(fc3_w, j * 1024 + k);
    u_part[jseg * 1024 + k] = acc;
}

// writes c0[0] = c0, c0[1] = c0 (init; mfma_sem's u-reduce atomicAdds SumU into c0[1])
template <int F>
DI void prep_c0(const void* fc3_b, const void* fca_w, const void* fca_b,
                float* c0, float* red) {
    float acc = 0.f;
    for (int j = threadIdx.x; j < 1024; j += 256)
        acc += LD<F>(fc3_b, j) * LD<F>(fca_w, j);
    red[threadIdx.x] = acc;
    __syncthreads();
    for (int s = 128; s > 0; s >>= 1) {
        if (threadIdx.x < s) red[threadIdx.x] += red[threadIdx.x + s];
        __syncthreads();
    }
    if (threadIdx.x == 0) {
        float v = red[0] + LD<F>(fca_b, 0);
        c0[0] = v;
        c0[1] = v;
    }
}

// ONE dispatch for all independent prep work (branch on block range)
__global__ __launch_bounds__(256) void mega_prep(
    const int* flag,
    const void* fmap, const void* fc1_w, const void* u5w,
    const void* w3, const void* w4, const void* w5, const void* u3,
    const void* fc3_w, const void* fc3_b, const void* fca_w, const void* fca_b,
    const void* word, const void* fc2_w, const void* fco_w,
    short* fmap_b, short* fc1w_b, short* u5w_b, short* wcat_b,
    short* word_b, short* fc2w_b, short* fcow_b,
    float* u_part, float* c0) {
    __shared__ float red[256];
    int f = *flag;
    int bid = blockIdx.x;
    if      (bid < 784)  cvt_part(f, fmap,  fmap_b, bid,        802816);
    else if (bid < 1808) cvt_part(f, fc1_w, fc1w_b, bid - 784,  1048576);
    else if (bid < 2832) cvt_part(f, u5w,   u5w_b,  bid - 1808, 1048576);
    else if (bid < 6928) wcat_part(f, w3, w4, w5, u3, wcat_b, bid - 2832);
    else if (bid < 6992) {
        if (f) prep_upart<1>(fc3_w, fca_w, u_part, bid - 6928);
        else   prep_upart<0>(fc3_w, fca_w, u_part, bid - 6928);
    } else if (bid == 6992) {
        if (f) prep_c0<1>(fc3_b, fca_w, fca_b, c0, red);
        else   prep_c0<0>(fc3_b, fca_w, fca_b, c0, red);
    }
    else if (bid < 7018) cvt_pad(f, word,  word_b, bid - 6993, 25600);
    else if (bid < 7338) cvt_pad(f, fc2_w, fc2w_b, bid - 7018, 327680);
    else                 cvt_part(f, fco_w, fcow_b, bid - 7338, 4194304);
}

// ================= bf16 MFMA GEMM core (proven R6) =================
DI void mcore_b(const short* __restrict__ A, int lda,
                const short* __restrict__ B, int ldb,
                float* __restrict__ C, int ldc,
                int M, int kb, int ke, int m0, int n0) {
    __shared__ short As[4][64][8];
    __shared__ short Ws[4][64][8];
    const int tid = threadIdx.x;
    const int wv = tid >> 6, lane = tid & 63;
    const int mA = tid & 63, qA = tid >> 6;
    f32x4 acc[4] = {};

    for (int k0 = kb; k0 < ke; k0 += 32) {
        s8v va = {0,0,0,0,0,0,0,0};
        int gm = m0 + mA;
        if (gm < M) va = *(const s8v*)(A + gm * lda + k0 + 8 * qA);
        *(s8v*)&As[mA >> 4][(mA & 15) | (qA << 4)][0] = va;
        s8v vb = *(const s8v*)(B + (n0 + mA) * ldb + k0 + 8 * qA);
        *(s8v*)&Ws[mA >> 4][(mA & 15) | (qA << 4)][0] = vb;
        __syncthreads();
        s8v af = *(const s8v*)&As[wv][lane][0];
#pragma unroll
        for (int nf = 0; nf < 4; nf++) {
            s8v bf = *(const s8v*)&Ws[nf][lane][0];
            acc[nf] = __builtin_amdgcn_mfma_f32_16x16x32_bf16(af, bf, acc[nf], 0, 0, 0);
        }
        __syncthreads();
    }

    const int q = lane >> 4, cc = lane & 15;
#pragma unroll
    for (int nf = 0; nf < 4; nf++) {
        int n = n0 + 16 * nf + cc;
#pragma unroll
        for (int r = 0; r < 4; r++) {
            int m = m0 + 16 * wv + q * 4 + r;
            if (m < M) C[m * ldc + n] = acc[nf][r];
        }
    }
}

// Semantic-stage MFMA bundle (proven R2):
__global__ __launch_bounds__(256) void mfma_sem(
    const short* __restrict__ fmap_b, const short* __restrict__ fc1w_b,
    const short* __restrict__ word_b, const short* __restrict__ fc2w_b,
    const float* __restrict__ u_part, float* __restrict__ u, float* __restrict__ c0,
    float* __restrict__ fhP, float* __restrict__ f_wd) {
    int bid = blockIdx.x;
    if (bid < 416) {
        int z = bid / 208, r = bid % 208;
        int by = r / 16, bx = r % 16;
        mcore_b(fmap_b, 1024, fc1w_b, 1024, fhP + z * 802816, 1024,
                NPIX, z * 512, z * 512 + 512, by * 64, bx * 64);
    } else if (bid < 448) {
        int r = bid - 416;
        int by = r >> 4, bx = r & 15;
        mcore_b(word_b, 320, fc2w_b, 320, f_wd, 1024,
                80, 0, 320, by * 64, bx * 64);
    } else {
        __shared__ float red[256];
        int k = (bid - 448) * 256 + threadIdx.x;
        float a = 0.f;
#pragma unroll
        for (int si = 0; si < 16; si++) a += u_part[si * 1024 + k];
        u[k] = a;
        red[threadIdx.x] = a;
        __syncthreads();
        for (int st = 128; st > 0; st >>= 1) {
            if (threadIdx.x < st) red[threadIdx.x] += red[threadIdx.x + st];
            __syncthreads();
        }
        if (threadIdx.x == 0) atomicAdd(c0 + 1, red[0]);
    }
}

__global__ __launch_bounds__(256) void mfma_gate(
    const short* __restrict__ a_b, const short* __restrict__ nodes_b,
    const short* __restrict__ wcat_b, float* __restrict__ gP) {
    int z = blockIdx.z;
    const short* A = (blockIdx.x >= 48) ? nodes_b : a_b;
    mcore_b(A, 1024, wcat_b, 1024, gP + z * 1310720, 4096,
            320, z * 512, z * 512 + 512, blockIdx.y * 64, blockIdx.x * 64);
}

// ---- u5 GEMM with ew_r fused into A-staging ----
// rn[m,c] = bf16( sigmoid(gP_r(m,c) + gP_x(m,c) + b4[c] + u3b[c]) * nodes[m,c] )
// computed inline (x16 redundant across bx blocks — gP is L2-resident, cheap);
// removes the ew_r dispatch and the rn_b round-trip. Same grid as proven mfma_u5.
__global__ __launch_bounds__(256) void mfma_u5f(
    const int* flag, const float* __restrict__ gP, const float* __restrict__ nodes,
    const void* b4, const void* u3b,
    const short* __restrict__ u5w_b, float* __restrict__ u5P) {
    __shared__ short As[4][64][8];
    __shared__ short Ws[4][64][8];
    __shared__ float bsum[256];
    const int tid = threadIdx.x;
    const int wv = tid >> 6, lane = tid & 63;
    const int mA = tid & 63, qA = tid >> 6;
    const int z = blockIdx.z;
    const int m0 = blockIdx.y * 64, n0 = blockIdx.x * 64;
    const int kb = z * 256;
    {
        int f = *flag;
        bsum[tid] = LDf(f, b4, kb + tid) + LDf(f, u3b, kb + tid);
    }
    __syncthreads();
    f32x4 acc[4] = {};

    for (int kk = 0; kk < 256; kk += 32) {
        int k0 = kb + kk;
        int gm = m0 + mA;
        int cb = k0 + 8 * qA;           // global channel base of the 8 staged elems
        int lb = kk + 8 * qA;           // bsum-local base
        const float* g0 = gP + gm * 4096;
        const float* g1 = gP + 1310720 + gm * 4096;
        const float* nd = nodes + gm * 1024;
        short ov[8];
#pragma unroll
        for (int h = 0; h < 2; h++) {
            int c = cb + 4 * h;
            float4 r0 = *(const float4*)(g0 + 1024 + c);
            float4 r1 = *(const float4*)(g1 + 1024 + c);
            float4 x0 = *(const float4*)(g0 + 3072 + c);
            float4 x1 = *(const float4*)(g1 + 3072 + c);
            float4 nv = *(const float4*)(nd + c);
            int lh = lb + 4 * h;
            ov[4*h+0] = f2b(fast_sigmoid(r0.x + r1.x + x0.x + x1.x + bsum[lh+0]) * nv.x);
            ov[4*h+1] = f2b(fast_sigmoid(r0.y + r1.y + x0.y + x1.y + bsum[lh+1]) * nv.y);
            ov[4*h+2] = f2b(fast_sigmoid(r0.z + r1.z + x0.z + x1.z + bsum[lh+2]) * nv.z);
            ov[4*h+3] = f2b(fast_sigmoid(r0.w + r1.w + x0.w + x1.w + bsum[lh+3]) * nv.w);
        }
        s8v va = { ov[0], ov[1], ov[2], ov[3], ov[4], ov[5], ov[6], ov[7] };
        *(s8v*)&As[mA >> 4][(mA & 15) | (qA << 4)][0] = va;
        s8v vb = *(const s8v*)(u5w_b + (n0 + mA) * 1024 + k0 + 8 * qA);
        *(s8v*)&Ws[mA >> 4][(mA & 15) | (qA << 4)][0] = vb;
        __syncthreads();
        s8v af = *(const s8v*)&As[wv][lane][0];
#pragma unroll
        for (int nf = 0; nf < 4; nf++) {
            s8v bf = *(const s8v*)&Ws[nf][lane][0];
            acc[nf] = __builtin_amdgcn_mfma_f32_16x16x32_bf16(af, bf, acc[nf], 0, 0, 0);
        }
        __syncthreads();
    }

    const int q = lane >> 4, cc = lane & 15;
    float* C = u5P + z * 327680;
#pragma unroll
    for (int nf = 0; nf < 4; nf++) {
        int n = n0 + 16 * nf + cc;
#pragma unroll
        for (int r = 0; r < 4; r++) {
            int m = m0 + 16 * wv + q * 4 + r;
            C[m * 1024 + n] = acc[nf][r];
        }
    }
}

__global__ __launch_bounds__(256) void mfma_fin(
    const short* __restrict__ nodes_b, const short* __restrict__ g_b,
    const short* __restrict__ fcow_b, float* __restrict__ finP) {
    int z = blockIdx.z;
    const short* A = z ? (g_b - 1024) : nodes_b;   // k in [1024,2048) maps into g_b
    mcore_b(A, 1024, fcow_b, 2048, finP + z * 655360, 2048,
            320, z * 1024, z * 1024 + 1024, blockIdx.y * 64, blockIdx.x * 64);
}

__global__ void fin_combine(const int* flag, const float* __restrict__ finP,
                            const void* fco_b, void* out, int n) {
    int i4 = (blockIdx.x * 256 + threadIdx.x) * 4;
    if (i4 >= n) return;
    int c = i4 & 2047;
    float4 p0 = *(const float4*)(finP + i4);
    float4 p1 = *(const float4*)(finP + 655360 + i4);
    int f = *flag;
    float v0 = fast_tanh(p0.x + p1.x + (f ? LD<1>(fco_b, c)   : LD<0>(fco_b, c)));
    float v1 = fast_tanh(p0.y + p1.y + (f ? LD<1>(fco_b, c+1) : LD<0>(fco_b, c+1)));
    float v2 = fast_tanh(p0.z + p1.z + (f ? LD<1>(fco_b, c+2) : LD<0>(fco_b, c+2)));
    float v3 = fast_tanh(p0.w + p1.w + (f ? LD<1>(fco_b, c+3) : LD<0>(fco_b, c+3)));
    if (f) {
        float4 o = {v0, v1, v2, v3};
        *(float4*)((float*)out + i4) = o;
    } else {
        short4v o = { f2b(v0), f2b(v1), f2b(v2), f2b(v3) };
        *(short4v*)((short*)out + i4) = o;
    }
}

// ---------------- coeff: 4 pixels/block, exp2+rcp algebra (proven R2) ----------------
__global__ __launch_bounds__(256) void coeff_kernel(
    const float* __restrict__ fhP, const float* __restrict__ f_wd,
    const float* __restrict__ u, const float* __restrict__ c0p,
    float* __restrict__ s) {
    __shared__ float h2s[4][1024];
    __shared__ float us[1024];
    const float K2 = 2.8853900817779268f;   // 2*log2(e)
    int t = threadIdx.x;
    int n0 = blockIdx.x * 4;
#pragma unroll
    for (int r = 0; r < 4; r++) {
        int n = n0 + r;
        float4 a0 = *(const float4*)(fhP + n * 1024 + t * 4);
        float4 a1 = *(const float4*)(fhP + 802816 + n * 1024 + t * 4);
        float4 hv = {K2 * (a0.x + a1.x), K2 * (a0.y + a1.y),
                     K2 * (a0.z + a1.z), K2 * (a0.w + a1.w)};
        *(float4*)&h2s[r][t * 4] = hv;
    }
    *(float4*)&us[t * 4] = *(const float4*)(u + t * 4);
    __syncthreads();
    float c0U = c0p[1];
    int wave = t >> 6, lane = t & 63;
    int b = n0 / 196, hw0 = n0 % 196;
    int l0 = blockIdx.y * 20;
    for (int l = l0 + wave; l < l0 + 20; l += 4) {
        const float4* fd4 = (const float4*)(f_wd + l * 1024);
        float p0 = 0.f, p1 = 0.f, p2 = 0.f, p3 = 0.f;
#pragma unroll
        for (int j = 0; j < 4; j++) {
            int idx = lane + j * 64;
            float4 d  = fd4[idx];
            float4 uu = *(const float4*)&us[idx * 4];
            float4 h0 = *(const float4*)&h2s[0][idx * 4];
            float4 h1 = *(const float4*)&h2s[1][idx * 4];
            float4 h2 = *(const float4*)&h2s[2][idx * 4];
            float4 h3 = *(const float4*)&h2s[3][idx * 4];
#define TERM(P, H) \
    P += uu.x * __builtin_amdgcn_rcpf(1.0f + __builtin_amdgcn_exp2f(H.x * d.x)); \
    P += uu.y * __builtin_amdgcn_rcpf(1.0f + __builtin_amdgcn_exp2f(H.y * d.y)); \
    P += uu.z * __builtin_amdgcn_rcpf(1.0f + __builtin_amdgcn_exp2f(H.z * d.z)); \
    P += uu.w * __builtin_amdgcn_rcpf(1.0f + __builtin_amdgcn_exp2f(H.w * d.w));
            TERM(p0, h0) TERM(p1, h1) TERM(p2, h2) TERM(p3, h3)
#undef TERM
        }
        for (int off = 32; off > 0; off >>= 1) {
            p0 += __shfl_down(p0, off);
            p1 += __shfl_down(p1, off);
            p2 += __shfl_down(p2, off);
            p3 += __shfl_down(p3, off);
        }
        if (lane == 0) {
            float* sp = s + b * PBATCH + hw0 * LL + l;
            sp[0]      = c0U - 2.f * p0;
            sp[LL]     = c0U - 2.f * p1;
            sp[2 * LL] = c0U - 2.f * p2;
            sp[3 * LL] = c0U - 2.f * p3;
        }
    }
}

// ---------------- softmax over CONTIGUOUS 196-chunks ----------------
// Faithful to torch's raw .view(b, L, h*w): chunks straddle (hw,l) fibers.
// Do NOT "fix" into a per-(b,l) softmax — R3 failed exactly on that.
__global__ __launch_bounds__(64) void softmax196(float* __restrict__ s) {
    float* p = s + blockIdx.x * 196;
    int lane = threadIdx.x;
    float v[4];
    float mx = -1e30f;
#pragma unroll
    for (int i = 0; i < 4; i++) {
        int idx = lane + i * 64;
        v[i] = (idx < 196) ? p[idx] : -1e30f;
        mx = fmaxf(mx, v[i]);
    }
    for (int off = 32; off > 0; off >>= 1) mx = fmaxf(mx, __shfl_down(mx, off));
    mx = __shfl(mx, 0);
    float sum = 0.f;
#pragma unroll
    for (int i = 0; i < 4; i++) {
        int idx = lane + i * 64;
        if (idx < 196) { v[i] = __expf(v[i] - mx); sum += v[i]; }
    }
    for (int off = 32; off > 0; off >>= 1) sum += __shfl_down(sum, off);
    sum = __shfl(sum, 0);
    float inv = 1.f / sum;
#pragma unroll
    for (int i = 0; i < 4; i++) {
        int idx = lane + i * 64;
        if (idx < 196) p[idx] = v[i] * inv;
    }
}

// ---------------- g: reads bf16 fmap_b, 4 c per thread ----------------
__global__ __launch_bounds__(256) void g_kernel(
    const float* __restrict__ s, const short* __restrict__ fmap_b,
    float* __restrict__ nodes, short* __restrict__ nodes_b, short* __restrict__ g_b) {
    int bl = blockIdx.x;
    int b = bl / LL, l = bl % LL;
    __shared__ float co[196];
    for (int i = threadIdx.x; i < 196; i += 256)
        co[i] = s[b * PBATCH + i * LL + l];
    __syncthreads();
    int c4 = threadIdx.x * 4;
    const short* base = fmap_b + b * 196 * 1024 + c4;
    float a0 = 0.f, a1 = 0.f, a2 = 0.f, a3 = 0.f;
    for (int hw = 0; hw < 196; hw++) {
        short4v v = *(const short4v*)(base + hw * 1024);
        float w = co[hw];
        a0 += w * s2f(v.x); a1 += w * s2f(v.y);
        a2 += w * s2f(v.z); a3 += w * s2f(v.w);
    }
    int o = bl * 1024 + c4;
    float4 fa = {a0, a1, a2, a3};
    *(float4*)(nodes + o) = fa;
    short4v bb = { f2b(a0), f2b(a1), f2b(a2), f2b(a3) };
    *(short4v*)(nodes_b + o) = bb;
    *(short4v*)(g_b + o) = bb;
}

// ---------------- adj: 4 c per thread ----------------
template <int F>
DI void adj_core(float* arw, const void* adj, const float* nodes, short* a_b) {
    int bl = blockIdx.x;
    int b = bl / LL, l = bl % LL;
    if (threadIdx.x < LL) arw[threadIdx.x] = LD<F>(adj, l * LL + threadIdx.x);
    __syncthreads();
    int c4 = threadIdx.x * 4;
    const float* nb = nodes + b * LL * 1024 + c4;
    float a0 = 0.f, a1 = 0.f, a2 = 0.f, a3 = 0.f;
    for (int m = 0; m < LL; m++) {
        float am = arw[m];
        float4 nd = *(const float4*)(nb + m * 1024);
        a0 += am * nd.x; a1 += am * nd.y; a2 += am * nd.z; a3 += am * nd.w;
    }
    short4v bb = { f2b(a0), f2b(a1), f2b(a2), f2b(a3) };
    *(short4v*)(a_b + bl * 1024 + c4) = bb;
}

__global__ __launch_bounds__(256) void adj_kernel(
    const int* flag, const void* adj, const float* nodes, short* a_b) {
    __shared__ float arw[LL];
    if (*flag) adj_core<1>(arw, adj, nodes, a_b);
    else       adj_core<0>(arw, adj, nodes, a_b);
}

// ---------------- nodes = (1-z)*nodes + z*tanh(ah+u5x+b5+u5b), z=sigmoid(az+u3x+b3+u3b), x4 ----------------
template <int F>
DI void ewu(const float* gP, const float* u5P,
            const void* b3, const void* u3b, const void* b5, const void* u5b,
            float* nodes, short* nodes_b, int i4) {
    int m = i4 >> 10, c = i4 & 1023;
    int base = m * 4096;
    float4 z0 = *(const float4*)(gP + base + c);
    float4 z1 = *(const float4*)(gP + 1310720 + base + c);
    float4 h0 = *(const float4*)(gP + base + 2048 + c);
    float4 h1 = *(const float4*)(gP + 1310720 + base + 2048 + c);
    float4 x0 = *(const float4*)(gP + base + 3072 + c);
    float4 x1 = *(const float4*)(gP + 1310720 + base + 3072 + c);
    float4 u0 = *(const float4*)(u5P + i4);
    float4 u1 = *(const float4*)(u5P + 327680 + i4);
    float4 u2 = *(const float4*)(u5P + 655360 + i4);
    float4 u3v = *(const float4*)(u5P + 983040 + i4);
    float4 nd = *(const float4*)(nodes + i4);
    float4 out;
#define EWU1(CH, CO) { \
    float z = fast_sigmoid(z0.CH + z1.CH + x0.CH + x1.CH + LD<F>(b3, c+CO) + LD<F>(u3b, c+CO)); \
    float h = fast_tanh(h0.CH + h1.CH + u0.CH + u1.CH + u2.CH + u3v.CH + LD<F>(b5, c+CO) + LD<F>(u5b, c+CO)); \
    out.CH = (1.f - z) * nd.CH + z * h; }
    EWU1(x, 0) EWU1(y, 1) EWU1(z, 2) EWU1(w, 3)
#undef EWU1
    *(float4*)(nodes + i4) = out;
    short4v bb = { f2b(out.x), f2b(out.y), f2b(out.z), f2b(out.w) };
    *(short4v*)(nodes_b + i4) = bb;
}

__global__ void ew_upd(const int* flag, const float* gP, const float* u5P,
                       const void* b3, const void* u3b, const void* b5, const void* u5b,
                       float* nodes, short* nodes_b, int n) {
    int i4 = (blockIdx.x * 256 + threadIdx.x) * 4;
    if (i4 >= n) return;
    if (*flag) ewu<1>(gP, u5P, b3, u3b, b5, u5b, nodes, nodes_b, i4);
    else       ewu<0>(gP, u5P, b3, u3b, b5, u5b, nodes, nodes_b, i4);
}

extern "C" void kernel_launch(void* const* d_in, const int* in_sizes, int n_in,
                              void* d_out, int out_size, void* d_ws, size_t ws_size,
                              hipStream_t stream) {
    const void* fmap  = d_in[0];
    const void* word  = d_in[1];
    const void* adjm  = d_in[2];
    const void* fc1_w = d_in[3];
    const void* fc2_w = d_in[4];
    const void* fc3_w = d_in[5];
    const void* fc3_b = d_in[6];
    const void* fca_w = d_in[7];
    const void* fca_b = d_in[8];
    const void* w3    = d_in[9];
    const void* b3    = d_in[10];
    const void* u3    = d_in[11];
    const void* u3b   = d_in[12];
    const void* w4    = d_in[13];
    const void* b4    = d_in[14];
    const void* w5    = d_in[15];
    const void* b5    = d_in[16];
    const void* u5    = d_in[17];
    const void* u5b   = d_in[18];
    const void* fco_w = d_in[19];
    const void* fco_b = d_in[20];

    // ---- workspace — increments are in FLOATS (bf16 buffers need elems/2).
    // Footprint ~37.9 MB (harness ws is ~268 MB).
    int*   flag    = (int*)d_ws;
    float* P       = (float*)d_ws + 16;
    float* nodes   = P;                       P += 327680;   // f32, persistent
    short* nodes_b = (short*)P;               P += 163840;   // 327680 bf16
    short* g_b     = (short*)P;               P += 163840;   // 327680 bf16
    short* a_b     = (short*)P;               P += 163840;   // 327680 bf16
    short* u5w_b   = (short*)P;               P += 524288;   // 1048576 bf16
    short* wcat_b  = (short*)P;               P += 2097152;  // 4194304 bf16 [4096][1024]
    short* fcow_b  = (short*)P;               P += 2097152;  // 4194304 bf16 [2048][2048]
    float* R       = P;                                      // overlay, 3,932,160 f
    // semantic phase
    float* fhP    = R;                        // 2 x 802816
    float* f_wd   = R + 1605632;              // 81920
    float* u_part = f_wd + 81920;             // 16 x 1024
    float* u      = u_part + 16384;           // 1024
    float* c0     = u + 1024;                 // 16 (c0[0]=c0, c0[1]=c0+SumU)
    float* s      = c0 + 16;                  // 62720
    short* fmap_b = (short*)(s + 62720);      // 802816 shorts
    short* fc1w_b = fmap_b + 802816;          // 1048576 shorts
    short* word_b = fc1w_b + 1048576;         // 80 x 320 shorts (K-padded)
    short* fc2w_b = word_b + 25600;           // 1024 x 320 shorts (K-padded)
    // GGNN phase (overlays semantic — all semantic buffers dead after g_kernel)
    float* gP     = R;                        // 2 x 1310720
    float* u5P    = R + 2621440;              // 4 x 327680
    // final phase (overlays GGNN)
    float* finP   = R;                        // 2 x 655360

    // ---- dtype detection ----
    detect_dtype<<<1, 256, 0, stream>>>(fc1_w, 4096, flag);

    // ---- all independent prep in ONE dispatch ----
    // blocks: 784 fmap | 1024 fc1 | 1024 u5 | 4096 wcat | 64 u_part | 1 c0
    //         | 25 word pad | 320 fc2_w pad | 4096 fco  => 11434
    mega_prep<<<11434, 256, 0, stream>>>(
        flag, fmap, fc1_w, u5, w3, w4, w5, u3,
        fc3_w, fc3_b, fca_w, fca_b, word, fc2_w, fco_w,
        fmap_b, fc1w_b, u5w_b, wcat_b, word_b, fc2w_b, fcow_b,
        u_part, c0);

    // ---- semantic stage ----
    mfma_sem<<<452, 256, 0, stream>>>(fmap_b, fc1w_b, word_b, fc2w_b,
                                      u_part, u, c0, fhP, f_wd);
    coeff_kernel<<<dim3(196, 4), 256, 0, stream>>>(fhP, f_wd, u, c0, s);
    softmax196<<<320, 64, 0, stream>>>(s);
    g_kernel<<<320, 256, 0, stream>>>(s, fmap_b, nodes, nodes_b, g_b);

    // ---- GGNN: 3 time steps, 4 dispatches each ----
    for (int t = 0; t < 3; t++) {
        adj_kernel<<<320, 256, 0, stream>>>(flag, adjm, nodes, a_b);
        mfma_gate<<<dim3(64, 5, 2), 256, 0, stream>>>(a_b, nodes_b, wcat_b, gP);
        mfma_u5f<<<dim3(16, 5, 4), 256, 0, stream>>>(flag, gP, nodes, b4, u3b,
                                                     u5w_b, u5P);
        ew_upd<<<320, 256, 0, stream>>>(flag, gP, u5P, b3, u3b, b5, u5b,
                                        nodes, nodes_b, 327680);
    }

    // ---- output: tanh([nodes|g] @ fco_w.T + fco_b) ----
    mfma_fin<<<dim3(32, 5, 2), 256, 0, stream>>>(nodes_b, g_b, fcow_b, finP);
    fin_combine<<<640, 256, 0, stream>>>(flag, finP, fco_b, d_out, 655360);
}

// Round 7
// 353.927 us; speedup vs baseline: 1.1178x; 1.1178x over previous
//
#include <hip/hip_runtime.h>
#include <hip/hip_bf16.h>

#define LL 80
#define NPIX 784
#define PBATCH 15680

#define DI __device__ __forceinline__

typedef short s8v __attribute__((ext_vector_type(8)));     // 8 bf16 = 16B
typedef short short4v __attribute__((ext_vector_type(4))); // 4 bf16 = 8B
typedef float f32x4 __attribute__((ext_vector_type(4)));   // MFMA acc

DI float b2f(__hip_bfloat16 x) { return __bfloat162float(x); }
DI float s2f(short h) { return __uint_as_float(((unsigned int)(unsigned short)h) << 16); }

// f32 -> bf16 bits, round-nearest-even
DI short f2b(float x) {
    unsigned int b = __float_as_uint(x);
    b += 0x7fffu + ((b >> 16) & 1u);
    return (short)(b >> 16);
}

// F=1: buffer holds f32; F=0: buffer holds bf16
template <int F> DI float LD(const void* p, int i) {
    if (F) return ((const float*)p)[i];
    return b2f(((const __hip_bfloat16*)p)[i]);
}
DI float LDf(int f, const void* p, int i) { return f ? ((const float*)p)[i] : b2f(((const __hip_bfloat16*)p)[i]); }

DI float fast_tanh(float x) {
    float e = __expf(2.0f * x);
    return 1.0f - 2.0f / (e + 1.0f);
}
DI float fast_sigmoid(float x) { return 1.0f / (1.0f + __expf(-x)); }

// ---------------- dtype probe (proven R3-R6) ----------------
__global__ __launch_bounds__(256) void detect_dtype(const void* probe, int n, int* flag) {
    __shared__ int bad;
    if (threadIdx.x == 0) bad = 0;
    __syncthreads();
    int c = 0;
    for (int i = threadIdx.x; i < n; i += 256) {
        float v = b2f(((const __hip_bfloat16*)probe)[i]);
        if (!(fabsf(v) < 1000.0f)) c++;
    }
    if (c) atomicAdd(&bad, c);
    __syncthreads();
    if (threadIdx.x == 0) *flag = (bad > 8) ? 1 : 0;   // 1 => inputs are f32
}

// ---------------- prep sub-parts ----------------
DI void cvt_part(int f, const void* src, short* __restrict__ dst, int blk, int n) {
    int i0 = (blk * 256 + threadIdx.x) * 4;
    if (i0 >= n) return;
    if (f) {
        float4 v = *(const float4*)((const float*)src + i0);
        short4v o = { f2b(v.x), f2b(v.y), f2b(v.z), f2b(v.w) };
        *(short4v*)(dst + i0) = o;
    } else {
        *(short4v*)(dst + i0) = *(const short4v*)((const short*)src + i0);
    }
}

// cvt with K-pad: src rows are 300 wide, dst rows 320 wide (zeros for k>=300)
DI void cvt_pad(int f, const void* src, short* __restrict__ dst, int blk, int n) {
    int i0 = (blk * 256 + threadIdx.x) * 4;
    if (i0 >= n) return;
    int row = i0 / 320;
    int k = i0 - row * 320;
    short4v o = {0, 0, 0, 0};
    if (k < 300) {
        if (f) {
            float4 v = *(const float4*)((const float*)src + row * 300 + k);
            o.x = f2b(v.x); o.y = f2b(v.y); o.z = f2b(v.z); o.w = f2b(v.w);
        } else {
            o = *(const short4v*)((const short*)src + row * 300 + k);
        }
    }
    *(short4v*)(dst + i0) = o;
}

// wcat[4096][1024]: rows 0-1023 w3 folded, 1024-2047 w4 folded, 2048-3071 w5 folded, 3072-4095 u3
// (proven R2 layout — R4's K-concat/interleave variant was latency-bound; keep this.)
DI void wcat_part(int f, const void* w3, const void* w4, const void* w5, const void* u3,
                  short* __restrict__ wcat, int blk) {
    int i0 = (blk * 256 + threadIdx.x) * 4;
    int nr = i0 >> 10, k = i0 & 1023;
    int j = nr >> 10, r = nr & 1023;
    const void* W = (j == 0) ? w3 : (j == 1) ? w4 : (j == 2) ? w5 : u3;
    float4 v;
    if (j < 3) {
        if (f) {
            float4 x = *(const float4*)((const float*)W + r * 2048 + k);
            float4 y = *(const float4*)((const float*)W + r * 2048 + 1024 + k);
            v.x = x.x + y.x; v.y = x.y + y.y; v.z = x.z + y.z; v.w = x.w + y.w;
        } else {
            const short* Ws = (const short*)W;
            short4v x = *(const short4v*)(Ws + r * 2048 + k);
            short4v y = *(const short4v*)(Ws + r * 2048 + 1024 + k);
            v.x = s2f(x.x) + s2f(y.x); v.y = s2f(x.y) + s2f(y.y);
            v.z = s2f(x.z) + s2f(y.z); v.w = s2f(x.w) + s2f(y.w);
        }
    } else {
        if (f) v = *(const float4*)((const float*)W + r * 1024 + k);
        else {
            short4v x = *(const short4v*)((const short*)W + r * 1024 + k);
            v.x = s2f(x.x); v.y = s2f(x.y); v.z = s2f(x.z); v.w = s2f(x.w);
        }
    }
    short4v o = { f2b(v.x), f2b(v.y), f2b(v.z), f2b(v.w) };
    *(short4v*)(wcat + i0) = o;
}

// u = fca_w @ fc3_w, split 16-way over j into partials.
template <int F>
DI void prep_upart(const void* fc3_w, const void* fca_w,
                   float* __restrict__ u_part, int blk) {
    int kseg = blk >> 4, jseg = blk & 15;
    int k = kseg * 256 + threadIdx.x;
    int j0 = jseg * 64;
    float acc = 0.f;
    for (int j = j0; j < j0 + 64; j++)
        acc += LD<F>(fca_w, j) * LD<F>(fc3_w, j * 1024 + k);
    u_part[jseg * 1024 + k] = acc;
}

// writes c0[0] = c0, c0[1] = c0 (init; mfma_sem's u-reduce atomicAdds SumU into c0[1])
template <int F>
DI void prep_c0(const void* fc3_b, const void* fca_w, const void* fca_b,
                float* c0, float* red) {
    float acc = 0.f;
    for (int j = threadIdx.x; j < 1024; j += 256)
        acc += LD<F>(fc3_b, j) * LD<F>(fca_w, j);
    red[threadIdx.x] = acc;
    __syncthreads();
    for (int s = 128; s > 0; s >>= 1) {
        if (threadIdx.x < s) red[threadIdx.x] += red[threadIdx.x + s];
        __syncthreads();
    }
    if (threadIdx.x == 0) {
        float v = red[0] + LD<F>(fca_b, 0);
        c0[0] = v;
        c0[1] = v;
    }
}

// ONE dispatch for all independent prep work (branch on block range)
__global__ __launch_bounds__(256) void mega_prep(
    const int* flag,
    const void* fmap, const void* fc1_w, const void* u5w,
    const void* w3, const void* w4, const void* w5, const void* u3,
    const void* fc3_w, const void* fc3_b, const void* fca_w, const void* fca_b,
    const void* word, const void* fc2_w, const void* fco_w,
    short* fmap_b, short* fc1w_b, short* u5w_b, short* wcat_b,
    short* word_b, short* fc2w_b, short* fcow_b,
    float* u_part, float* c0) {
    __shared__ float red[256];
    int f = *flag;
    int bid = blockIdx.x;
    if      (bid < 784)  cvt_part(f, fmap,  fmap_b, bid,        802816);
    else if (bid < 1808) cvt_part(f, fc1_w, fc1w_b, bid - 784,  1048576);
    else if (bid < 2832) cvt_part(f, u5w,   u5w_b,  bid - 1808, 1048576);
    else if (bid < 6928) wcat_part(f, w3, w4, w5, u3, wcat_b, bid - 2832);
    else if (bid < 6992) {
        if (f) prep_upart<1>(fc3_w, fca_w, u_part, bid - 6928);
        else   prep_upart<0>(fc3_w, fca_w, u_part, bid - 6928);
    } else if (bid == 6992) {
        if (f) prep_c0<1>(fc3_b, fca_w, fca_b, c0, red);
        else   prep_c0<0>(fc3_b, fca_w, fca_b, c0, red);
    }
    else if (bid < 7018) cvt_pad(f, word,  word_b, bid - 6993, 25600);
    else if (bid < 7338) cvt_pad(f, fc2_w, fc2w_b, bid - 7018, 327680);
    else                 cvt_part(f, fco_w, fcow_b, bid - 7338, 4194304);
}

// ================= bf16 MFMA GEMM core (proven R6) =================
DI void mcore_b(const short* __restrict__ A, int lda,
                const short* __restrict__ B, int ldb,
                float* __restrict__ C, int ldc,
                int M, int kb, int ke, int m0, int n0) {
    __shared__ short As[4][64][8];
    __shared__ short Ws[4][64][8];
    const int tid = threadIdx.x;
    const int wv = tid >> 6, lane = tid & 63;
    const int mA = tid & 63, qA = tid >> 6;
    f32x4 acc[4] = {};

    for (int k0 = kb; k0 < ke; k0 += 32) {
        s8v va = {0,0,0,0,0,0,0,0};
        int gm = m0 + mA;
        if (gm < M) va = *(const s8v*)(A + gm * lda + k0 + 8 * qA);
        *(s8v*)&As[mA >> 4][(mA & 15) | (qA << 4)][0] = va;
        s8v vb = *(const s8v*)(B + (n0 + mA) * ldb + k0 + 8 * qA);
        *(s8v*)&Ws[mA >> 4][(mA & 15) | (qA << 4)][0] = vb;
        __syncthreads();
        s8v af = *(const s8v*)&As[wv][lane][0];
#pragma unroll
        for (int nf = 0; nf < 4; nf++) {
            s8v bf = *(const s8v*)&Ws[nf][lane][0];
            acc[nf] = __builtin_amdgcn_mfma_f32_16x16x32_bf16(af, bf, acc[nf], 0, 0, 0);
        }
        __syncthreads();
    }

    const int q = lane >> 4, cc = lane & 15;
#pragma unroll
    for (int nf = 0; nf < 4; nf++) {
        int n = n0 + 16 * nf + cc;
#pragma unroll
        for (int r = 0; r < 4; r++) {
            int m = m0 + 16 * wv + q * 4 + r;
            if (m < M) C[m * ldc + n] = acc[nf][r];
        }
    }
}

// acc-returning core with mid-K A-switch (Aa for k<ksw, Ab at k-ksw after).
// Used only by mfma_finC where M=320 (multiple of 64) — no m-masking needed.
DI void mcore_acc(const short* __restrict__ Aa, const short* __restrict__ Ab, int ksw,
                  int lda, const short* __restrict__ B, int ldb,
                  int kb, int ke, int m0, int n0, f32x4* acc) {
    __shared__ short As[4][64][8];
    __shared__ short Ws[4][64][8];
    const int tid = threadIdx.x;
    const int wv = tid >> 6, lane = tid & 63;
    const int mA = tid & 63, qA = tid >> 6;

    for (int k0 = kb; k0 < ke; k0 += 32) {
        const short* Ar = (k0 < ksw) ? (Aa + (m0 + mA) * lda + k0)
                                     : (Ab + (m0 + mA) * lda + (k0 - ksw));
        s8v va = *(const s8v*)(Ar + 8 * qA);
        *(s8v*)&As[mA >> 4][(mA & 15) | (qA << 4)][0] = va;
        s8v vb = *(const s8v*)(B + (n0 + mA) * ldb + k0 + 8 * qA);
        *(s8v*)&Ws[mA >> 4][(mA & 15) | (qA << 4)][0] = vb;
        __syncthreads();
        s8v af = *(const s8v*)&As[wv][lane][0];
#pragma unroll
        for (int nf = 0; nf < 4; nf++) {
            s8v bf = *(const s8v*)&Ws[nf][lane][0];
            acc[nf] = __builtin_amdgcn_mfma_f32_16x16x32_bf16(af, bf, acc[nf], 0, 0, 0);
        }
        __syncthreads();
    }
}

// Semantic-stage MFMA bundle (proven R2):
__global__ __launch_bounds__(256) void mfma_sem(
    const short* __restrict__ fmap_b, const short* __restrict__ fc1w_b,
    const short* __restrict__ word_b, const short* __restrict__ fc2w_b,
    const float* __restrict__ u_part, float* __restrict__ u, float* __restrict__ c0,
    float* __restrict__ fhP, float* __restrict__ f_wd) {
    int bid = blockIdx.x;
    if (bid < 416) {
        int z = bid / 208, r = bid % 208;
        int by = r / 16, bx = r % 16;
        mcore_b(fmap_b, 1024, fc1w_b, 1024, fhP + z * 802816, 1024,
                NPIX, z * 512, z * 512 + 512, by * 64, bx * 64);
    } else if (bid < 448) {
        int r = bid - 416;
        int by = r >> 4, bx = r & 15;
        mcore_b(word_b, 320, fc2w_b, 320, f_wd, 1024,
                80, 0, 320, by * 64, bx * 64);
    } else {
        __shared__ float red[256];
        int k = (bid - 448) * 256 + threadIdx.x;
        float a = 0.f;
#pragma unroll
        for (int si = 0; si < 16; si++) a += u_part[si * 1024 + k];
        u[k] = a;
        red[threadIdx.x] = a;
        __syncthreads();
        for (int st = 128; st > 0; st >>= 1) {
            if (threadIdx.x < st) red[threadIdx.x] += red[threadIdx.x + st];
            __syncthreads();
        }
        if (threadIdx.x == 0) atomicAdd(c0 + 1, red[0]);
    }
}

__global__ __launch_bounds__(256) void mfma_gate(
    const short* __restrict__ a_b, const short* __restrict__ nodes_b,
    const short* __restrict__ wcat_b, float* __restrict__ gP) {
    int z = blockIdx.z;
    const short* A = (blockIdx.x >= 48) ? nodes_b : a_b;
    mcore_b(A, 1024, wcat_b, 1024, gP + z * 1310720, 4096,
            320, z * 512, z * 512 + 512, blockIdx.y * 64, blockIdx.x * 64);
}

__global__ __launch_bounds__(256) void mfma_u5(
    const short* __restrict__ rn_b, const short* __restrict__ u5w_b,
    float* __restrict__ u5P) {
    int z = blockIdx.z;
    mcore_b(rn_b, 1024, u5w_b, 1024, u5P + z * 327680, 1024,
            320, z * 256, z * 256 + 256, blockIdx.y * 64, blockIdx.x * 64);
}

// ---- fused fin: out = tanh([nodes|g] @ fco_w.T + fco_b), written directly ----
// Full K=2048 with A-switch at 1024. 160 blocks all-concurrent: same 64-iter
// critical path as the old z-split (which doubled up on 64 CUs), but the finP
// round-trip (21 MB) and the fin_combine dispatch disappear. Epilogue is
// per-lane-register local — no row-gather (R6's trap).
__global__ __launch_bounds__(256) void mfma_finC(
    const int* flag,
    const short* __restrict__ nodes_b, const short* __restrict__ g_b,
    const short* __restrict__ fcow_b, const void* fco_b, void* out) {
    f32x4 acc[4] = {};
    int m0 = blockIdx.y * 64, n0 = blockIdx.x * 64;
    mcore_acc(nodes_b, g_b, 1024, 1024, fcow_b, 2048, 0, 2048, m0, n0, acc);
    const int tid = threadIdx.x;
    const int wv = tid >> 6, lane = tid & 63;
    const int q = lane >> 4, cc = lane & 15;
    const int f = *flag;
#pragma unroll
    for (int nf = 0; nf < 4; nf++) {
        int n = n0 + 16 * nf + cc;
        float bb = LDf(f, fco_b, n);
#pragma unroll
        for (int r = 0; r < 4; r++) {
            int m = m0 + 16 * wv + q * 4 + r;
            float v = fast_tanh(acc[nf][r] + bb);
            if (f) ((float*)out)[m * 2048 + n] = v;
            else   ((short*)out)[m * 2048 + n] = f2b(v);
        }
    }
}

// ---------------- coeff: 4 pixels/block, exp2+rcp algebra (proven R2) ----------------
__global__ __launch_bounds__(256) void coeff_kernel(
    const float* __restrict__ fhP, const float* __restrict__ f_wd,
    const float* __restrict__ u, const float* __restrict__ c0p,
    float* __restrict__ s) {
    __shared__ float h2s[4][1024];
    __shared__ float us[1024];
    const float K2 = 2.8853900817779268f;   // 2*log2(e)
    int t = threadIdx.x;
    int n0 = blockIdx.x * 4;
#pragma unroll
    for (int r = 0; r < 4; r++) {
        int n = n0 + r;
        float4 a0 = *(const float4*)(fhP + n * 1024 + t * 4);
        float4 a1 = *(const float4*)(fhP + 802816 + n * 1024 + t * 4);
        float4 hv = {K2 * (a0.x + a1.x), K2 * (a0.y + a1.y),
                     K2 * (a0.z + a1.z), K2 * (a0.w + a1.w)};
        *(float4*)&h2s[r][t * 4] = hv;
    }
    *(float4*)&us[t * 4] = *(const float4*)(u + t * 4);
    __syncthreads();
    float c0U = c0p[1];
    int wave = t >> 6, lane = t & 63;
    int b = n0 / 196, hw0 = n0 % 196;
    int l0 = blockIdx.y * 20;
    for (int l = l0 + wave; l < l0 + 20; l += 4) {
        const float4* fd4 = (const float4*)(f_wd + l * 1024);
        float p0 = 0.f, p1 = 0.f, p2 = 0.f, p3 = 0.f;
#pragma unroll
        for (int j = 0; j < 4; j++) {
            int idx = lane + j * 64;
            float4 d  = fd4[idx];
            float4 uu = *(const float4*)&us[idx * 4];
            float4 h0 = *(const float4*)&h2s[0][idx * 4];
            float4 h1 = *(const float4*)&h2s[1][idx * 4];
            float4 h2 = *(const float4*)&h2s[2][idx * 4];
            float4 h3 = *(const float4*)&h2s[3][idx * 4];
#define TERM(P, H) \
    P += uu.x * __builtin_amdgcn_rcpf(1.0f + __builtin_amdgcn_exp2f(H.x * d.x)); \
    P += uu.y * __builtin_amdgcn_rcpf(1.0f + __builtin_amdgcn_exp2f(H.y * d.y)); \
    P += uu.z * __builtin_amdgcn_rcpf(1.0f + __builtin_amdgcn_exp2f(H.z * d.z)); \
    P += uu.w * __builtin_amdgcn_rcpf(1.0f + __builtin_amdgcn_exp2f(H.w * d.w));
            TERM(p0, h0) TERM(p1, h1) TERM(p2, h2) TERM(p3, h3)
#undef TERM
        }
        for (int off = 32; off > 0; off >>= 1) {
            p0 += __shfl_down(p0, off);
            p1 += __shfl_down(p1, off);
            p2 += __shfl_down(p2, off);
            p3 += __shfl_down(p3, off);
        }
        if (lane == 0) {
            float* sp = s + b * PBATCH + hw0 * LL + l;
            sp[0]      = c0U - 2.f * p0;
            sp[LL]     = c0U - 2.f * p1;
            sp[2 * LL] = c0U - 2.f * p2;
            sp[3 * LL] = c0U - 2.f * p3;
        }
    }
}

// ---------------- softmax over CONTIGUOUS 196-chunks ----------------
// Faithful to torch's raw .view(b, L, h*w): chunks straddle (hw,l) fibers.
// Do NOT "fix" into a per-(b,l) softmax — R3 failed exactly on that.
__global__ __launch_bounds__(64) void softmax196(float* __restrict__ s) {
    float* p = s + blockIdx.x * 196;
    int lane = threadIdx.x;
    float v[4];
    float mx = -1e30f;
#pragma unroll
    for (int i = 0; i < 4; i++) {
        int idx = lane + i * 64;
        v[i] = (idx < 196) ? p[idx] : -1e30f;
        mx = fmaxf(mx, v[i]);
    }
    for (int off = 32; off > 0; off >>= 1) mx = fmaxf(mx, __shfl_down(mx, off));
    mx = __shfl(mx, 0);
    float sum = 0.f;
#pragma unroll
    for (int i = 0; i < 4; i++) {
        int idx = lane + i * 64;
        if (idx < 196) { v[i] = __expf(v[i] - mx); sum += v[i]; }
    }
    for (int off = 32; off > 0; off >>= 1) sum += __shfl_down(sum, off);
    sum = __shfl(sum, 0);
    float inv = 1.f / sum;
#pragma unroll
    for (int i = 0; i < 4; i++) {
        int idx = lane + i * 64;
        if (idx < 196) p[idx] = v[i] * inv;
    }
}

// ---------------- g: reads bf16 fmap_b, 4 c per thread ----------------
__global__ __launch_bounds__(256) void g_kernel(
    const float* __restrict__ s, const short* __restrict__ fmap_b,
    float* __restrict__ nodes, short* __restrict__ nodes_b, short* __restrict__ g_b) {
    int bl = blockIdx.x;
    int b = bl / LL, l = bl % LL;
    __shared__ float co[196];
    for (int i = threadIdx.x; i < 196; i += 256)
        co[i] = s[b * PBATCH + i * LL + l];
    __syncthreads();
    int c4 = threadIdx.x * 4;
    const short* base = fmap_b + b * 196 * 1024 + c4;
    float a0 = 0.f, a1 = 0.f, a2 = 0.f, a3 = 0.f;
    for (int hw = 0; hw < 196; hw++) {
        short4v v = *(const short4v*)(base + hw * 1024);
        float w = co[hw];
        a0 += w * s2f(v.x); a1 += w * s2f(v.y);
        a2 += w * s2f(v.z); a3 += w * s2f(v.w);
    }
    int o = bl * 1024 + c4;
    float4 fa = {a0, a1, a2, a3};
    *(float4*)(nodes + o) = fa;
    short4v bb = { f2b(a0), f2b(a1), f2b(a2), f2b(a3) };
    *(short4v*)(nodes_b + o) = bb;
    *(short4v*)(g_b + o) = bb;
}

// ---------------- adj: 4 c per thread ----------------
template <int F>
DI void adj_core(float* arw, const void* adj, const float* nodes, short* a_b) {
    int bl = blockIdx.x;
    int b = bl / LL, l = bl % LL;
    if (threadIdx.x < LL) arw[threadIdx.x] = LD<F>(adj, l * LL + threadIdx.x);
    __syncthreads();
    int c4 = threadIdx.x * 4;
    const float* nb = nodes + b * LL * 1024 + c4;
    float a0 = 0.f, a1 = 0.f, a2 = 0.f, a3 = 0.f;
    for (int m = 0; m < LL; m++) {
        float am = arw[m];
        float4 nd = *(const float4*)(nb + m * 1024);
        a0 += am * nd.x; a1 += am * nd.y; a2 += am * nd.z; a3 += am * nd.w;
    }
    short4v bb = { f2b(a0), f2b(a1), f2b(a2), f2b(a3) };
    *(short4v*)(a_b + bl * 1024 + c4) = bb;
}

__global__ __launch_bounds__(256) void adj_kernel(
    const int* flag, const void* adj, const float* nodes, short* a_b) {
    __shared__ float arw[LL];
    if (*flag) adj_core<1>(arw, adj, nodes, a_b);
    else       adj_core<0>(arw, adj, nodes, a_b);
}

// ---------------- rn_b = bf16( sigmoid(ar + u3x + b4 + u3b) * nodes ), x4 ----------------
template <int F>
DI void ew_r_core(const float* gP, const float* nodes,
                  const void* b4, const void* u3b, short* rn_b, int i4) {
    int m = i4 >> 10, c = i4 & 1023;
    int base = m * 4096;
    float4 r0 = *(const float4*)(gP + base + 1024 + c);
    float4 r1 = *(const float4*)(gP + 1310720 + base + 1024 + c);
    float4 x0 = *(const float4*)(gP + base + 3072 + c);
    float4 x1 = *(const float4*)(gP + 1310720 + base + 3072 + c);
    float4 nd = *(const float4*)(nodes + i4);
    short4v o;
    o.x = f2b(fast_sigmoid(r0.x + r1.x + x0.x + x1.x + LD<F>(b4, c)   + LD<F>(u3b, c))   * nd.x);
    o.y = f2b(fast_sigmoid(r0.y + r1.y + x0.y + x1.y + LD<F>(b4, c+1) + LD<F>(u3b, c+1)) * nd.y);
    o.z = f2b(fast_sigmoid(r0.z + r1.z + x0.z + x1.z + LD<F>(b4, c+2) + LD<F>(u3b, c+2)) * nd.z);
    o.w = f2b(fast_sigmoid(r0.w + r1.w + x0.w + x1.w + LD<F>(b4, c+3) + LD<F>(u3b, c+3)) * nd.w);
    *(short4v*)(rn_b + i4) = o;
}

__global__ void ew_r(const int* flag, const float* gP, const float* nodes,
                     const void* b4, const void* u3b, short* rn_b, int n) {
    int i4 = (blockIdx.x * 256 + threadIdx.x) * 4;
    if (i4 >= n) return;
    if (*flag) ew_r_core<1>(gP, nodes, b4, u3b, rn_b, i4);
    else       ew_r_core<0>(gP, nodes, b4, u3b, rn_b, i4);
}

// ---------------- nodes = (1-z)*nodes + z*tanh(ah+u5x+b5+u5b), z=sigmoid(az+u3x+b3+u3b), x4 ----------------
template <int F>
DI void ewu(const float* gP, const float* u5P,
            const void* b3, const void* u3b, const void* b5, const void* u5b,
            float* nodes, short* nodes_b, int i4) {
    int m = i4 >> 10, c = i4 & 1023;
    int base = m * 4096;
    float4 z0 = *(const float4*)(gP + base + c);
    float4 z1 = *(const float4*)(gP + 1310720 + base + c);
    float4 h0 = *(const float4*)(gP + base + 2048 + c);
    float4 h1 = *(const float4*)(gP + 1310720 + base + 2048 + c);
    float4 x0 = *(const float4*)(gP + base + 3072 + c);
    float4 x1 = *(const float4*)(gP + 1310720 + base + 3072 + c);
    float4 u0 = *(const float4*)(u5P + i4);
    float4 u1 = *(const float4*)(u5P + 327680 + i4);
    float4 u2 = *(const float4*)(u5P + 655360 + i4);
    float4 u3v = *(const float4*)(u5P + 983040 + i4);
    float4 nd = *(const float4*)(nodes + i4);
    float4 out;
#define EWU1(CH, CO) { \
    float z = fast_sigmoid(z0.CH + z1.CH + x0.CH + x1.CH + LD<F>(b3, c+CO) + LD<F>(u3b, c+CO)); \
    float h = fast_tanh(h0.CH + h1.CH + u0.CH + u1.CH + u2.CH + u3v.CH + LD<F>(b5, c+CO) + LD<F>(u5b, c+CO)); \
    out.CH = (1.f - z) * nd.CH + z * h; }
    EWU1(x, 0) EWU1(y, 1) EWU1(z, 2) EWU1(w, 3)
#undef EWU1
    *(float4*)(nodes + i4) = out;
    short4v bb = { f2b(out.x), f2b(out.y), f2b(out.z), f2b(out.w) };
    *(short4v*)(nodes_b + i4) = bb;
}

__global__ void ew_upd(const int* flag, const float* gP, const float* u5P,
                       const void* b3, const void* u3b, const void* b5, const void* u5b,
                       float* nodes, short* nodes_b, int n) {
    int i4 = (blockIdx.x * 256 + threadIdx.x) * 4;
    if (i4 >= n) return;
    if (*flag) ewu<1>(gP, u5P, b3, u3b, b5, u5b, nodes, nodes_b, i4);
    else       ewu<0>(gP, u5P, b3, u3b, b5, u5b, nodes, nodes_b, i4);
}

extern "C" void kernel_launch(void* const* d_in, const int* in_sizes, int n_in,
                              void* d_out, int out_size, void* d_ws, size_t ws_size,
                              hipStream_t stream) {
    const void* fmap  = d_in[0];
    const void* word  = d_in[1];
    const void* adjm  = d_in[2];
    const void* fc1_w = d_in[3];
    const void* fc2_w = d_in[4];
    const void* fc3_w = d_in[5];
    const void* fc3_b = d_in[6];
    const void* fca_w = d_in[7];
    const void* fca_b = d_in[8];
    const void* w3    = d_in[9];
    const void* b3    = d_in[10];
    const void* u3    = d_in[11];
    const void* u3b   = d_in[12];
    const void* w4    = d_in[13];
    const void* b4    = d_in[14];
    const void* w5    = d_in[15];
    const void* b5    = d_in[16];
    const void* u5    = d_in[17];
    const void* u5b   = d_in[18];
    const void* fco_w = d_in[19];
    const void* fco_b = d_in[20];

    // ---- workspace — increments are in FLOATS (bf16 buffers need elems/2).
    // Footprint ~38.5 MB (harness ws ≈ 268 MB).
    int*   flag    = (int*)d_ws;
    float* P       = (float*)d_ws + 16;
    float* nodes   = P;                       P += 327680;   // f32, persistent
    short* nodes_b = (short*)P;               P += 163840;   // 327680 bf16
    short* g_b     = (short*)P;               P += 163840;   // 327680 bf16
    short* a_b     = (short*)P;               P += 163840;   // 327680 bf16
    short* rn_b    = (short*)P;               P += 163840;   // 327680 bf16
    short* u5w_b   = (short*)P;               P += 524288;   // 1048576 bf16
    short* wcat_b  = (short*)P;               P += 2097152;  // 4194304 bf16 [4096][1024]
    short* fcow_b  = (short*)P;               P += 2097152;  // 4194304 bf16 [2048][2048], dedicated
    float* R       = P;                                      // overlay, 3,932,160 f
    // semantic phase
    float* fhP    = R;                        // 2 x 802816
    float* f_wd   = R + 1605632;              // 81920
    float* u_part = f_wd + 81920;             // 16 x 1024
    float* u      = u_part + 16384;           // 1024
    float* c0     = u + 1024;                 // 16 (c0[0]=c0, c0[1]=c0+SumU)
    float* s      = c0 + 16;                  // 62720
    short* fmap_b = (short*)(s + 62720);      // 802816 shorts
    short* fc1w_b = fmap_b + 802816;          // 1048576 shorts
    short* word_b = fc1w_b + 1048576;         // 80 x 320 shorts (K-padded)
    short* fc2w_b = word_b + 25600;           // 1024 x 320 shorts (K-padded)
    // GGNN phase (overlays semantic — all semantic buffers dead after g_kernel)
    float* gP     = R;                        // 2 x 1310720
    float* u5P    = R + 2621440;              // 4 x 327680

    // ---- dtype detection ----
    detect_dtype<<<1, 256, 0, stream>>>(fc1_w, 4096, flag);

    // ---- all independent prep in ONE dispatch ----
    // blocks: 784 fmap | 1024 fc1 | 1024 u5 | 4096 wcat | 64 u_part | 1 c0
    //         | 25 word pad | 320 fc2_w pad | 4096 fco  => 11434
    mega_prep<<<11434, 256, 0, stream>>>(
        flag, fmap, fc1_w, u5, w3, w4, w5, u3,
        fc3_w, fc3_b, fca_w, fca_b, word, fc2_w, fco_w,
        fmap_b, fc1w_b, u5w_b, wcat_b, word_b, fc2w_b, fcow_b,
        u_part, c0);

    // ---- semantic stage ----
    mfma_sem<<<452, 256, 0, stream>>>(fmap_b, fc1w_b, word_b, fc2w_b,
                                      u_part, u, c0, fhP, f_wd);
    coeff_kernel<<<dim3(196, 4), 256, 0, stream>>>(fhP, f_wd, u, c0, s);
    softmax196<<<320, 64, 0, stream>>>(s);
    g_kernel<<<320, 256, 0, stream>>>(s, fmap_b, nodes, nodes_b, g_b);

    // ---- GGNN: 3 time steps, 5 dispatches each (proven R2 structure) ----
    for (int t = 0; t < 3; t++) {
        adj_kernel<<<320, 256, 0, stream>>>(flag, adjm, nodes, a_b);
        mfma_gate<<<dim3(64, 5, 2), 256, 0, stream>>>(a_b, nodes_b, wcat_b, gP);
        ew_r<<<320, 256, 0, stream>>>(flag, gP, nodes, b4, u3b, rn_b, 327680);
        mfma_u5<<<dim3(16, 5, 4), 256, 0, stream>>>(rn_b, u5w_b, u5P);
        ew_upd<<<320, 256, 0, stream>>>(flag, gP, u5P, b3, u3b, b5, u5b,
                                        nodes, nodes_b, 327680);
    }

    // ---- output: fused fin GEMM + bias + tanh -> d_out ----
    mfma_finC<<<dim3(32, 5), 256, 0, stream>>>(flag, nodes_b, g_b, fcow_b,
                                               fco_b, d_out);
}

// Round 8
// 325.361 us; speedup vs baseline: 1.2160x; 1.0878x over previous
//
#include <hip/hip_runtime.h>
#include <hip/hip_bf16.h>

#define LL 80
#define NPIX 784
#define PBATCH 15680

#define DI __device__ __forceinline__

typedef short s8v __attribute__((ext_vector_type(8)));     // 8 bf16 = 16B
typedef short short4v __attribute__((ext_vector_type(4))); // 4 bf16 = 8B
typedef float f32x4 __attribute__((ext_vector_type(4)));   // MFMA acc

DI float b2f(__hip_bfloat16 x) { return __bfloat162float(x); }
DI float s2f(short h) { return __uint_as_float(((unsigned int)(unsigned short)h) << 16); }

// f32 -> bf16 bits, round-nearest-even
DI short f2b(float x) {
    unsigned int b = __float_as_uint(x);
    b += 0x7fffu + ((b >> 16) & 1u);
    return (short)(b >> 16);
}

// F=1: buffer holds f32; F=0: buffer holds bf16
template <int F> DI float LD(const void* p, int i) {
    if (F) return ((const float*)p)[i];
    return b2f(((const __hip_bfloat16*)p)[i]);
}
DI float LDf(int f, const void* p, int i) { return f ? ((const float*)p)[i] : b2f(((const __hip_bfloat16*)p)[i]); }

DI float fast_tanh(float x) {
    float e = __expf(2.0f * x);
    return 1.0f - 2.0f / (e + 1.0f);
}
DI float fast_sigmoid(float x) { return 1.0f / (1.0f + __expf(-x)); }

// ---------------- dtype probe (proven R3-R6) ----------------
__global__ __launch_bounds__(256) void detect_dtype(const void* probe, int n, int* flag) {
    __shared__ int bad;
    if (threadIdx.x == 0) bad = 0;
    __syncthreads();
    int c = 0;
    for (int i = threadIdx.x; i < n; i += 256) {
        float v = b2f(((const __hip_bfloat16*)probe)[i]);
        if (!(fabsf(v) < 1000.0f)) c++;
    }
    if (c) atomicAdd(&bad, c);
    __syncthreads();
    if (threadIdx.x == 0) *flag = (bad > 8) ? 1 : 0;   // 1 => inputs are f32
}

// ---------------- prep sub-parts ----------------
DI void cvt_part(int f, const void* src, short* __restrict__ dst, int blk, int n) {
    int i0 = (blk * 256 + threadIdx.x) * 4;
    if (i0 >= n) return;
    if (f) {
        float4 v = *(const float4*)((const float*)src + i0);
        short4v o = { f2b(v.x), f2b(v.y), f2b(v.z), f2b(v.w) };
        *(short4v*)(dst + i0) = o;
    } else {
        *(short4v*)(dst + i0) = *(const short4v*)((const short*)src + i0);
    }
}

// cvt with K-pad: src rows are 300 wide, dst rows 320 wide (zeros for k>=300)
DI void cvt_pad(int f, const void* src, short* __restrict__ dst, int blk, int n) {
    int i0 = (blk * 256 + threadIdx.x) * 4;
    if (i0 >= n) return;
    int row = i0 / 320;
    int k = i0 - row * 320;
    short4v o = {0, 0, 0, 0};
    if (k < 300) {
        if (f) {
            float4 v = *(const float4*)((const float*)src + row * 300 + k);
            o.x = f2b(v.x); o.y = f2b(v.y); o.z = f2b(v.z); o.w = f2b(v.w);
        } else {
            o = *(const short4v*)((const short*)src + row * 300 + k);
        }
    }
    *(short4v*)(dst + i0) = o;
}

// wcat[4096][1024]: rows 0-1023 w3 folded, 1024-2047 w4 folded, 2048-3071 w5 folded, 3072-4095 u3
// (proven R2 layout — R4's K-concat/interleave variant was latency-bound; keep this.)
DI void wcat_part(int f, const void* w3, const void* w4, const void* w5, const void* u3,
                  short* __restrict__ wcat, int blk) {
    int i0 = (blk * 256 + threadIdx.x) * 4;
    int nr = i0 >> 10, k = i0 & 1023;
    int j = nr >> 10, r = nr & 1023;
    const void* W = (j == 0) ? w3 : (j == 1) ? w4 : (j == 2) ? w5 : u3;
    float4 v;
    if (j < 3) {
        if (f) {
            float4 x = *(const float4*)((const float*)W + r * 2048 + k);
            float4 y = *(const float4*)((const float*)W + r * 2048 + 1024 + k);
            v.x = x.x + y.x; v.y = x.y + y.y; v.z = x.z + y.z; v.w = x.w + y.w;
        } else {
            const short* Ws = (const short*)W;
            short4v x = *(const short4v*)(Ws + r * 2048 + k);
            short4v y = *(const short4v*)(Ws + r * 2048 + 1024 + k);
            v.x = s2f(x.x) + s2f(y.x); v.y = s2f(x.y) + s2f(y.y);
            v.z = s2f(x.z) + s2f(y.z); v.w = s2f(x.w) + s2f(y.w);
        }
    } else {
        if (f) v = *(const float4*)((const float*)W + r * 1024 + k);
        else {
            short4v x = *(const short4v*)((const short*)W + r * 1024 + k);
            v.x = s2f(x.x); v.y = s2f(x.y); v.z = s2f(x.z); v.w = s2f(x.w);
        }
    }
    short4v o = { f2b(v.x), f2b(v.y), f2b(v.z), f2b(v.w) };
    *(short4v*)(wcat + i0) = o;
}

// u = fca_w @ fc3_w, split 16-way over j into partials.
template <int F>
DI void prep_upart(const void* fc3_w, const void* fca_w,
                   float* __restrict__ u_part, int blk) {
    int kseg = blk >> 4, jseg = blk & 15;
    int k = kseg * 256 + threadIdx.x;
    int j0 = jseg * 64;
    float acc = 0.f;
    for (int j = j0; j < j0 + 64; j++)
        acc += LD<F>(fca_w, j) * LD<F>(fc3_w, j * 1024 + k);
    u_part[jseg * 1024 + k] = acc;
}

// writes c0[0] = c0, c0[1] = c0 (init; mfma_sem's u-reduce atomicAdds SumU into c0[1])
template <int F>
DI void prep_c0(const void* fc3_b, const void* fca_w, const void* fca_b,
                float* c0, float* red) {
    float acc = 0.f;
    for (int j = threadIdx.x; j < 1024; j += 256)
        acc += LD<F>(fc3_b, j) * LD<F>(fca_w, j);
    red[threadIdx.x] = acc;
    __syncthreads();
    for (int s = 128; s > 0; s >>= 1) {
        if (threadIdx.x < s) red[threadIdx.x] += red[threadIdx.x + s];
        __syncthreads();
    }
    if (threadIdx.x == 0) {
        float v = red[0] + LD<F>(fca_b, 0);
        c0[0] = v;
        c0[1] = v;
    }
}

// ONE dispatch for all independent prep work (branch on block range)
__global__ __launch_bounds__(256) void mega_prep(
    const int* flag,
    const void* fmap, const void* fc1_w, const void* u5w,
    const void* w3, const void* w4, const void* w5, const void* u3,
    const void* fc3_w, const void* fc3_b, const void* fca_w, const void* fca_b,
    const void* word, const void* fc2_w, const void* fco_w,
    short* fmap_b, short* fc1w_b, short* u5w_b, short* wcat_b,
    short* word_b, short* fc2w_b, short* fcow_b,
    float* u_part, float* c0) {
    __shared__ float red[256];
    int f = *flag;
    int bid = blockIdx.x;
    if      (bid < 784)  cvt_part(f, fmap,  fmap_b, bid,        802816);
    else if (bid < 1808) cvt_part(f, fc1_w, fc1w_b, bid - 784,  1048576);
    else if (bid < 2832) cvt_part(f, u5w,   u5w_b,  bid - 1808, 1048576);
    else if (bid < 6928) wcat_part(f, w3, w4, w5, u3, wcat_b, bid - 2832);
    else if (bid < 6992) {
        if (f) prep_upart<1>(fc3_w, fca_w, u_part, bid - 6928);
        else   prep_upart<0>(fc3_w, fca_w, u_part, bid - 6928);
    } else if (bid == 6992) {
        if (f) prep_c0<1>(fc3_b, fca_w, fca_b, c0, red);
        else   prep_c0<0>(fc3_b, fca_w, fca_b, c0, red);
    }
    else if (bid < 7018) cvt_pad(f, word,  word_b, bid - 6993, 25600);
    else if (bid < 7338) cvt_pad(f, fc2_w, fc2w_b, bid - 7018, 327680);
    else                 cvt_part(f, fco_w, fcow_b, bid - 7338, 4194304);
}

// ================= bf16 MFMA GEMM core, register-prefetch version =================
// R7 PMC showed ~750 ns per k-iteration (MfmaUtil 1.9% on finC): the single-
// buffered loop serialized a full global-load latency each iteration. Here the
// NEXT tile's loads are issued right after the current tile's LDS write — their
// waitcnt lands after compute + 2 barriers instead of immediately, hiding a
// few hundred ns/iter. Same loads, same single-LDS-buffer discipline (the
// prefetched regs are written only after the compute-done barrier).
DI void mcore_b(const short* __restrict__ A, int lda,
                const short* __restrict__ B, int ldb,
                float* __restrict__ C, int ldc,
                int M, int kb, int ke, int m0, int n0) {
    __shared__ short As[4][64][8];
    __shared__ short Ws[4][64][8];
    const int tid = threadIdx.x;
    const int wv = tid >> 6, lane = tid & 63;
    const int mA = tid & 63, qA = tid >> 6;
    const int gm = m0 + mA;
    const short* Arow = A + gm * lda + 8 * qA;
    const short* Brow = B + (n0 + mA) * ldb + 8 * qA;
    f32x4 acc[4] = {};

    s8v va = {0,0,0,0,0,0,0,0};
    if (gm < M) va = *(const s8v*)(Arow + kb);
    s8v vb = *(const s8v*)(Brow + kb);

    for (int k0 = kb; k0 < ke; k0 += 32) {
        *(s8v*)&As[mA >> 4][(mA & 15) | (qA << 4)][0] = va;
        *(s8v*)&Ws[mA >> 4][(mA & 15) | (qA << 4)][0] = vb;
        int k1 = k0 + 32;
        if (k1 < ke) {
            if (gm < M) va = *(const s8v*)(Arow + k1);
            vb = *(const s8v*)(Brow + k1);
        }
        __syncthreads();
        s8v af = *(const s8v*)&As[wv][lane][0];
#pragma unroll
        for (int nf = 0; nf < 4; nf++) {
            s8v bf = *(const s8v*)&Ws[nf][lane][0];
            acc[nf] = __builtin_amdgcn_mfma_f32_16x16x32_bf16(af, bf, acc[nf], 0, 0, 0);
        }
        __syncthreads();
    }

    const int q = lane >> 4, cc = lane & 15;
#pragma unroll
    for (int nf = 0; nf < 4; nf++) {
        int n = n0 + 16 * nf + cc;
#pragma unroll
        for (int r = 0; r < 4; r++) {
            int m = m0 + 16 * wv + q * 4 + r;
            if (m < M) C[m * ldc + n] = acc[nf][r];
        }
    }
}

// Semantic-stage MFMA bundle (proven R2):
__global__ __launch_bounds__(256) void mfma_sem(
    const short* __restrict__ fmap_b, const short* __restrict__ fc1w_b,
    const short* __restrict__ word_b, const short* __restrict__ fc2w_b,
    const float* __restrict__ u_part, float* __restrict__ u, float* __restrict__ c0,
    float* __restrict__ fhP, float* __restrict__ f_wd) {
    int bid = blockIdx.x;
    if (bid < 416) {
        int z = bid / 208, r = bid % 208;
        int by = r / 16, bx = r % 16;
        mcore_b(fmap_b, 1024, fc1w_b, 1024, fhP + z * 802816, 1024,
                NPIX, z * 512, z * 512 + 512, by * 64, bx * 64);
    } else if (bid < 448) {
        int r = bid - 416;
        int by = r >> 4, bx = r & 15;
        mcore_b(word_b, 320, fc2w_b, 320, f_wd, 1024,
                80, 0, 320, by * 64, bx * 64);
    } else {
        __shared__ float red[256];
        int k = (bid - 448) * 256 + threadIdx.x;
        float a = 0.f;
#pragma unroll
        for (int si = 0; si < 16; si++) a += u_part[si * 1024 + k];
        u[k] = a;
        red[threadIdx.x] = a;
        __syncthreads();
        for (int st = 128; st > 0; st >>= 1) {
            if (threadIdx.x < st) red[threadIdx.x] += red[threadIdx.x + st];
            __syncthreads();
        }
        if (threadIdx.x == 0) atomicAdd(c0 + 1, red[0]);
    }
}

__global__ __launch_bounds__(256) void mfma_gate(
    const short* __restrict__ a_b, const short* __restrict__ nodes_b,
    const short* __restrict__ wcat_b, float* __restrict__ gP) {
    int z = blockIdx.z;
    const short* A = (blockIdx.x >= 48) ? nodes_b : a_b;
    mcore_b(A, 1024, wcat_b, 1024, gP + z * 1310720, 4096,
            320, z * 512, z * 512 + 512, blockIdx.y * 64, blockIdx.x * 64);
}

__global__ __launch_bounds__(256) void mfma_u5(
    const short* __restrict__ rn_b, const short* __restrict__ u5w_b,
    float* __restrict__ u5P) {
    int z = blockIdx.z;
    mcore_b(rn_b, 1024, u5w_b, 1024, u5P + z * 327680, 1024,
            320, z * 256, z * 256 + 256, blockIdx.y * 64, blockIdx.x * 64);
}

// ---- fin: 4-way K-split (R7 lesson: K=2048 at 1 block/CU was 750 ns/iter
// latency-serial, 48 µs). (32,5,4)=640 blocks, 16 iters each, 2.5 blocks/CU.
// z<2 reads nodes_b (k in [0,1024)); z>=2 reads g_b via the -1024 pointer trick.
__global__ __launch_bounds__(256) void mfma_fin(
    const short* __restrict__ nodes_b, const short* __restrict__ g_b,
    const short* __restrict__ fcow_b, float* __restrict__ finP) {
    int z = blockIdx.z;
    const short* A = (z < 2) ? nodes_b : (g_b - 1024);
    mcore_b(A, 1024, fcow_b, 2048, finP + z * 655360, 2048,
            320, z * 512, z * 512 + 512, blockIdx.y * 64, blockIdx.x * 64);
}

__global__ void fin_combine(const int* flag, const float* __restrict__ finP,
                            const void* fco_b, void* out, int n) {
    int i4 = (blockIdx.x * 256 + threadIdx.x) * 4;
    if (i4 >= n) return;
    int c = i4 & 2047;
    float4 p0 = *(const float4*)(finP + i4);
    float4 p1 = *(const float4*)(finP + 655360 + i4);
    float4 p2 = *(const float4*)(finP + 1310720 + i4);
    float4 p3 = *(const float4*)(finP + 1966080 + i4);
    int f = *flag;
    float v0 = fast_tanh(p0.x + p1.x + p2.x + p3.x + LDf(f, fco_b, c));
    float v1 = fast_tanh(p0.y + p1.y + p2.y + p3.y + LDf(f, fco_b, c + 1));
    float v2 = fast_tanh(p0.z + p1.z + p2.z + p3.z + LDf(f, fco_b, c + 2));
    float v3 = fast_tanh(p0.w + p1.w + p2.w + p3.w + LDf(f, fco_b, c + 3));
    if (f) {
        float4 o = {v0, v1, v2, v3};
        *(float4*)((float*)out + i4) = o;
    } else {
        short4v o = { f2b(v0), f2b(v1), f2b(v2), f2b(v3) };
        *(short4v*)((short*)out + i4) = o;
    }
}

// ---------------- coeff: 4 pixels/block, exp2+rcp algebra (proven R2) ----------------
__global__ __launch_bounds__(256) void coeff_kernel(
    const float* __restrict__ fhP, const float* __restrict__ f_wd,
    const float* __restrict__ u, const float* __restrict__ c0p,
    float* __restrict__ s) {
    __shared__ float h2s[4][1024];
    __shared__ float us[1024];
    const float K2 = 2.8853900817779268f;   // 2*log2(e)
    int t = threadIdx.x;
    int n0 = blockIdx.x * 4;
#pragma unroll
    for (int r = 0; r < 4; r++) {
        int n = n0 + r;
        float4 a0 = *(const float4*)(fhP + n * 1024 + t * 4);
        float4 a1 = *(const float4*)(fhP + 802816 + n * 1024 + t * 4);
        float4 hv = {K2 * (a0.x + a1.x), K2 * (a0.y + a1.y),
                     K2 * (a0.z + a1.z), K2 * (a0.w + a1.w)};
        *(float4*)&h2s[r][t * 4] = hv;
    }
    *(float4*)&us[t * 4] = *(const float4*)(u + t * 4);
    __syncthreads();
    float c0U = c0p[1];
    int wave = t >> 6, lane = t & 63;
    int b = n0 / 196, hw0 = n0 % 196;
    int l0 = blockIdx.y * 20;
    for (int l = l0 + wave; l < l0 + 20; l += 4) {
        const float4* fd4 = (const float4*)(f_wd + l * 1024);
        float p0 = 0.f, p1 = 0.f, p2 = 0.f, p3 = 0.f;
#pragma unroll
        for (int j = 0; j < 4; j++) {
            int idx = lane + j * 64;
            float4 d  = fd4[idx];
            float4 uu = *(const float4*)&us[idx * 4];
            float4 h0 = *(const float4*)&h2s[0][idx * 4];
            float4 h1 = *(const float4*)&h2s[1][idx * 4];
            float4 h2 = *(const float4*)&h2s[2][idx * 4];
            float4 h3 = *(const float4*)&h2s[3][idx * 4];
#define TERM(P, H) \
    P += uu.x * __builtin_amdgcn_rcpf(1.0f + __builtin_amdgcn_exp2f(H.x * d.x)); \
    P += uu.y * __builtin_amdgcn_rcpf(1.0f + __builtin_amdgcn_exp2f(H.y * d.y)); \
    P += uu.z * __builtin_amdgcn_rcpf(1.0f + __builtin_amdgcn_exp2f(H.z * d.z)); \
    P += uu.w * __builtin_amdgcn_rcpf(1.0f + __builtin_amdgcn_exp2f(H.w * d.w));
            TERM(p0, h0) TERM(p1, h1) TERM(p2, h2) TERM(p3, h3)
#undef TERM
        }
        for (int off = 32; off > 0; off >>= 1) {
            p0 += __shfl_down(p0, off);
            p1 += __shfl_down(p1, off);
            p2 += __shfl_down(p2, off);
            p3 += __shfl_down(p3, off);
        }
        if (lane == 0) {
            float* sp = s + b * PBATCH + hw0 * LL + l;
            sp[0]      = c0U - 2.f * p0;
            sp[LL]     = c0U - 2.f * p1;
            sp[2 * LL] = c0U - 2.f * p2;
            sp[3 * LL] = c0U - 2.f * p3;
        }
    }
}

// ---------------- softmax over CONTIGUOUS 196-chunks ----------------
// Faithful to torch's raw .view(b, L, h*w): chunks straddle (hw,l) fibers.
// Do NOT "fix" into a per-(b,l) softmax — R3 failed exactly on that.
__global__ __launch_bounds__(64) void softmax196(float* __restrict__ s) {
    float* p = s + blockIdx.x * 196;
    int lane = threadIdx.x;
    float v[4];
    float mx = -1e30f;
#pragma unroll
    for (int i = 0; i < 4; i++) {
        int idx = lane + i * 64;
        v[i] = (idx < 196) ? p[idx] : -1e30f;
        mx = fmaxf(mx, v[i]);
    }
    for (int off = 32; off > 0; off >>= 1) mx = fmaxf(mx, __shfl_down(mx, off));
    mx = __shfl(mx, 0);
    float sum = 0.f;
#pragma unroll
    for (int i = 0; i < 4; i++) {
        int idx = lane + i * 64;
        if (idx < 196) { v[i] = __expf(v[i] - mx); sum += v[i]; }
    }
    for (int off = 32; off > 0; off >>= 1) sum += __shfl_down(sum, off);
    sum = __shfl(sum, 0);
    float inv = 1.f / sum;
#pragma unroll
    for (int i = 0; i < 4; i++) {
        int idx = lane + i * 64;
        if (idx < 196) p[idx] = v[i] * inv;
    }
}

// ---------------- g: reads bf16 fmap_b, 4 c per thread ----------------
__global__ __launch_bounds__(256) void g_kernel(
    const float* __restrict__ s, const short* __restrict__ fmap_b,
    float* __restrict__ nodes, short* __restrict__ nodes_b, short* __restrict__ g_b) {
    int bl = blockIdx.x;
    int b = bl / LL, l = bl % LL;
    __shared__ float co[196];
    for (int i = threadIdx.x; i < 196; i += 256)
        co[i] = s[b * PBATCH + i * LL + l];
    __syncthreads();
    int c4 = threadIdx.x * 4;
    const short* base = fmap_b + b * 196 * 1024 + c4;
    float a0 = 0.f, a1 = 0.f, a2 = 0.f, a3 = 0.f;
    for (int hw = 0; hw < 196; hw++) {
        short4v v = *(const short4v*)(base + hw * 1024);
        float w = co[hw];
        a0 += w * s2f(v.x); a1 += w * s2f(v.y);
        a2 += w * s2f(v.z); a3 += w * s2f(v.w);
    }
    int o = bl * 1024 + c4;
    float4 fa = {a0, a1, a2, a3};
    *(float4*)(nodes + o) = fa;
    short4v bb = { f2b(a0), f2b(a1), f2b(a2), f2b(a3) };
    *(short4v*)(nodes_b + o) = bb;
    *(short4v*)(g_b + o) = bb;
}

// ---------------- adj: 4 c per thread ----------------
template <int F>
DI void adj_core(float* arw, const void* adj, const float* nodes, short* a_b) {
    int bl = blockIdx.x;
    int b = bl / LL, l = bl % LL;
    if (threadIdx.x < LL) arw[threadIdx.x] = LD<F>(adj, l * LL + threadIdx.x);
    __syncthreads();
    int c4 = threadIdx.x * 4;
    const float* nb = nodes + b * LL * 1024 + c4;
    float a0 = 0.f, a1 = 0.f, a2 = 0.f, a3 = 0.f;
    for (int m = 0; m < LL; m++) {
        float am = arw[m];
        float4 nd = *(const float4*)(nb + m * 1024);
        a0 += am * nd.x; a1 += am * nd.y; a2 += am * nd.z; a3 += am * nd.w;
    }
    short4v bb = { f2b(a0), f2b(a1), f2b(a2), f2b(a3) };
    *(short4v*)(a_b + bl * 1024 + c4) = bb;
}

__global__ __launch_bounds__(256) void adj_kernel(
    const int* flag, const void* adj, const float* nodes, short* a_b) {
    __shared__ float arw[LL];
    if (*flag) adj_core<1>(arw, adj, nodes, a_b);
    else       adj_core<0>(arw, adj, nodes, a_b);
}

// ---------------- rn_b = bf16( sigmoid(ar + u3x + b4 + u3b) * nodes ), x4 ----------------
template <int F>
DI void ew_r_core(const float* gP, const float* nodes,
                  const void* b4, const void* u3b, short* rn_b, int i4) {
    int m = i4 >> 10, c = i4 & 1023;
    int base = m * 4096;
    float4 r0 = *(const float4*)(gP + base + 1024 + c);
    float4 r1 = *(const float4*)(gP + 1310720 + base + 1024 + c);
    float4 x0 = *(const float4*)(gP + base + 3072 + c);
    float4 x1 = *(const float4*)(gP + 1310720 + base + 3072 + c);
    float4 nd = *(const float4*)(nodes + i4);
    short4v o;
    o.x = f2b(fast_sigmoid(r0.x + r1.x + x0.x + x1.x + LD<F>(b4, c)   + LD<F>(u3b, c))   * nd.x);
    o.y = f2b(fast_sigmoid(r0.y + r1.y + x0.y + x1.y + LD<F>(b4, c+1) + LD<F>(u3b, c+1)) * nd.y);
    o.z = f2b(fast_sigmoid(r0.z + r1.z + x0.z + x1.z + LD<F>(b4, c+2) + LD<F>(u3b, c+2)) * nd.z);
    o.w = f2b(fast_sigmoid(r0.w + r1.w + x0.w + x1.w + LD<F>(b4, c+3) + LD<F>(u3b, c+3)) * nd.w);
    *(short4v*)(rn_b + i4) = o;
}

__global__ void ew_r(const int* flag, const float* gP, const float* nodes,
                     const void* b4, const void* u3b, short* rn_b, int n) {
    int i4 = (blockIdx.x * 256 + threadIdx.x) * 4;
    if (i4 >= n) return;
    if (*flag) ew_r_core<1>(gP, nodes, b4, u3b, rn_b, i4);
    else       ew_r_core<0>(gP, nodes, b4, u3b, rn_b, i4);
}

// ---------------- nodes = (1-z)*nodes + z*tanh(ah+u5x+b5+u5b), z=sigmoid(az+u3x+b3+u3b), x4 ----------------
template <int F>
DI void ewu(const float* gP, const float* u5P,
            const void* b3, const void* u3b, const void* b5, const void* u5b,
            float* nodes, short* nodes_b, int i4) {
    int m = i4 >> 10, c = i4 & 1023;
    int base = m * 4096;
    float4 z0 = *(const float4*)(gP + base + c);
    float4 z1 = *(const float4*)(gP + 1310720 + base + c);
    float4 h0 = *(const float4*)(gP + base + 2048 + c);
    float4 h1 = *(const float4*)(gP + 1310720 + base + 2048 + c);
    float4 x0 = *(const float4*)(gP + base + 3072 + c);
    float4 x1 = *(const float4*)(gP + 1310720 + base + 3072 + c);
    float4 u0 = *(const float4*)(u5P + i4);
    float4 u1 = *(const float4*)(u5P + 327680 + i4);
    float4 u2 = *(const float4*)(u5P + 655360 + i4);
    float4 u3v = *(const float4*)(u5P + 983040 + i4);
    float4 nd = *(const float4*)(nodes + i4);
    float4 out;
#define EWU1(CH, CO) { \
    float z = fast_sigmoid(z0.CH + z1.CH + x0.CH + x1.CH + LD<F>(b3, c+CO) + LD<F>(u3b, c+CO)); \
    float h = fast_tanh(h0.CH + h1.CH + u0.CH + u1.CH + u2.CH + u3v.CH + LD<F>(b5, c+CO) + LD<F>(u5b, c+CO)); \
    out.CH = (1.f - z) * nd.CH + z * h; }
    EWU1(x, 0) EWU1(y, 1) EWU1(z, 2) EWU1(w, 3)
#undef EWU1
    *(float4*)(nodes + i4) = out;
    short4v bb = { f2b(out.x), f2b(out.y), f2b(out.z), f2b(out.w) };
    *(short4v*)(nodes_b + i4) = bb;
}

__global__ void ew_upd(const int* flag, const float* gP, const float* u5P,
                       const void* b3, const void* u3b, const void* b5, const void* u5b,
                       float* nodes, short* nodes_b, int n) {
    int i4 = (blockIdx.x * 256 + threadIdx.x) * 4;
    if (i4 >= n) return;
    if (*flag) ewu<1>(gP, u5P, b3, u3b, b5, u5b, nodes, nodes_b, i4);
    else       ewu<0>(gP, u5P, b3, u3b, b5, u5b, nodes, nodes_b, i4);
}

extern "C" void kernel_launch(void* const* d_in, const int* in_sizes, int n_in,
                              void* d_out, int out_size, void* d_ws, size_t ws_size,
                              hipStream_t stream) {
    const void* fmap  = d_in[0];
    const void* word  = d_in[1];
    const void* adjm  = d_in[2];
    const void* fc1_w = d_in[3];
    const void* fc2_w = d_in[4];
    const void* fc3_w = d_in[5];
    const void* fc3_b = d_in[6];
    const void* fca_w = d_in[7];
    const void* fca_b = d_in[8];
    const void* w3    = d_in[9];
    const void* b3    = d_in[10];
    const void* u3    = d_in[11];
    const void* u3b   = d_in[12];
    const void* w4    = d_in[13];
    const void* b4    = d_in[14];
    const void* w5    = d_in[15];
    const void* b5    = d_in[16];
    const void* u5    = d_in[17];
    const void* u5b   = d_in[18];
    const void* fco_w = d_in[19];
    const void* fco_b = d_in[20];

    // ---- workspace — increments are in FLOATS (bf16 buffers need elems/2).
    // Footprint ~38.5 MB (harness ws ≈ 268 MB).
    int*   flag    = (int*)d_ws;
    float* P       = (float*)d_ws + 16;
    float* nodes   = P;                       P += 327680;   // f32, persistent
    short* nodes_b = (short*)P;               P += 163840;   // 327680 bf16
    short* g_b     = (short*)P;               P += 163840;   // 327680 bf16
    short* a_b     = (short*)P;               P += 163840;   // 327680 bf16
    short* rn_b    = (short*)P;               P += 163840;   // 327680 bf16
    short* u5w_b   = (short*)P;               P += 524288;   // 1048576 bf16
    short* wcat_b  = (short*)P;               P += 2097152;  // 4194304 bf16 [4096][1024]
    short* fcow_b  = (short*)P;               P += 2097152;  // 4194304 bf16 [2048][2048], dedicated
    float* R       = P;                                      // overlay, 3,932,160 f
    // semantic phase
    float* fhP    = R;                        // 2 x 802816
    float* f_wd   = R + 1605632;              // 81920
    float* u_part = f_wd + 81920;             // 16 x 1024
    float* u      = u_part + 16384;           // 1024
    float* c0     = u + 1024;                 // 16 (c0[0]=c0, c0[1]=c0+SumU)
    float* s      = c0 + 16;                  // 62720
    short* fmap_b = (short*)(s + 62720);      // 802816 shorts
    short* fc1w_b = fmap_b + 802816;          // 1048576 shorts
    short* word_b = fc1w_b + 1048576;         // 80 x 320 shorts (K-padded)
    short* fc2w_b = word_b + 25600;           // 1024 x 320 shorts (K-padded)
    // GGNN phase (overlays semantic — all semantic buffers dead after g_kernel)
    float* gP     = R;                        // 2 x 1310720
    float* u5P    = R + 2621440;              // 4 x 327680
    // final phase (overlays GGNN; gP/u5P dead after last ew_upd)
    float* finP   = R;                        // 4 x 655360

    // ---- dtype detection ----
    detect_dtype<<<1, 256, 0, stream>>>(fc1_w, 4096, flag);

    // ---- all independent prep in ONE dispatch ----
    // blocks: 784 fmap | 1024 fc1 | 1024 u5 | 4096 wcat | 64 u_part | 1 c0
    //         | 25 word pad | 320 fc2_w pad | 4096 fco  => 11434
    mega_prep<<<11434, 256, 0, stream>>>(
        flag, fmap, fc1_w, u5, w3, w4, w5, u3,
        fc3_w, fc3_b, fca_w, fca_b, word, fc2_w, fco_w,
        fmap_b, fc1w_b, u5w_b, wcat_b, word_b, fc2w_b, fcow_b,
        u_part, c0);

    // ---- semantic stage ----
    mfma_sem<<<452, 256, 0, stream>>>(fmap_b, fc1w_b, word_b, fc2w_b,
                                      u_part, u, c0, fhP, f_wd);
    coeff_kernel<<<dim3(196, 4), 256, 0, stream>>>(fhP, f_wd, u, c0, s);
    softmax196<<<320, 64, 0, stream>>>(s);
    g_kernel<<<320, 256, 0, stream>>>(s, fmap_b, nodes, nodes_b, g_b);

    // ---- GGNN: 3 time steps, 5 dispatches each (proven R2 structure) ----
    for (int t = 0; t < 3; t++) {
        adj_kernel<<<320, 256, 0, stream>>>(flag, adjm, nodes, a_b);
        mfma_gate<<<dim3(64, 5, 2), 256, 0, stream>>>(a_b, nodes_b, wcat_b, gP);
        ew_r<<<320, 256, 0, stream>>>(flag, gP, nodes, b4, u3b, rn_b, 327680);
        mfma_u5<<<dim3(16, 5, 4), 256, 0, stream>>>(rn_b, u5w_b, u5P);
        ew_upd<<<320, 256, 0, stream>>>(flag, gP, u5P, b3, u3b, b5, u5b,
                                        nodes, nodes_b, 327680);
    }

    // ---- output: 4-way K-split fin GEMM + combine ----
    mfma_fin<<<dim3(32, 5, 4), 256, 0, stream>>>(nodes_b, g_b, fcow_b, finP);
    fin_combine<<<640, 256, 0, stream>>>(flag, finP, fco_b, d_out, 655360);
}